// Round 11
// baseline (217.184 us; speedup 1.0000x reference)
//
#include <hip/hip_runtime.h>
#include <hip/hip_bf16.h>
#include <cstdint>

#define TOKENS 4096
#define DMODEL 512
#define NEXP 8
#define DFF 2048

typedef short s16x8 __attribute__((ext_vector_type(8)));
typedef short s16x4 __attribute__((ext_vector_type(4)));
typedef float f32x4 __attribute__((ext_vector_type(4)));
typedef unsigned int u32x2 __attribute__((ext_vector_type(2)));

#define MEMFENCE asm volatile("" ::: "memory")

__device__ __forceinline__ float bf2f(short h) {
    unsigned int u = ((unsigned int)(unsigned short)h) << 16;
    return __uint_as_float(u);
}
__device__ __forceinline__ short f2bf(float f) {
    unsigned int u = __float_as_uint(f);
    u += 0x7fffu + ((u >> 16) & 1u);
    return (short)(u >> 16);
}
__device__ __forceinline__ unsigned int cvtpk_bf16(float a, float b) {
    unsigned int r;
    asm volatile("v_cvt_pk_bf16_f32 %0, %1, %2" : "=v"(r) : "v"(a), "v"(b));
    return r;
}
// exact pair: gelu(x0)+gelu(x1) with single rcp; tanh-form, constants pre-scaled by log2(e)
#define GP_C0 2.3022084f
#define GP_C1 0.10294330f
__device__ __forceinline__ float gelu_pair(float x0, float x1) {
    float z0 = x0 * fmaf(x0 * x0, GP_C1, GP_C0);
    float z1 = x1 * fmaf(x1 * x1, GP_C1, GP_C0);
    float e0 = __builtin_amdgcn_exp2f(z0);
    float e1 = __builtin_amdgcn_exp2f(z1);
    float t0 = 1.0f + e0, t1 = 1.0f + e1;
    float R = __builtin_amdgcn_rcpf(t0 * t1);
    float num = fmaf(x0, t1, x1 * t0);
    return fmaf(-num, R, x0 + x1);
}
__device__ __forceinline__ void gload_lds16(const void* g, void* l) {
    __builtin_amdgcn_global_load_lds((const __attribute__((address_space(1))) void*)g,
                                     (__attribute__((address_space(3))) void*)l, 16, 0, 0);
}

// ---------------- gate (+ x->bf16 fused) ----------------
__global__ void gate_cvt_kernel(const float* __restrict__ x, const float* __restrict__ Wg,
                                float* __restrict__ s0, float* __restrict__ s1,
                                short* __restrict__ xb) {
    int wave = threadIdx.x >> 6;
    int lane = threadIdx.x & 63;
    int t = blockIdx.x * 4 + wave;
    const float* xr = x + (size_t)t * DMODEL + lane * 8;
    float4 xa = *(const float4*)(xr);
    float4 xv2 = *(const float4*)(xr + 4);
    float xv[8] = {xa.x, xa.y, xa.z, xa.w, xv2.x, xv2.y, xv2.z, xv2.w};
    s16x8 v;
#pragma unroll
    for (int j = 0; j < 8; j++) v[j] = f2bf(xv[j]);
    *(s16x8*)&xb[(size_t)t * DMODEL + lane * 8] = v;

    float lg[8];
#pragma unroll
    for (int e = 0; e < 8; e++) lg[e] = 0.f;
#pragma unroll
    for (int j = 0; j < 8; j++) {
        const float4* wr = (const float4*)(Wg + (size_t)(lane * 8 + j) * NEXP);
        float4 wa = wr[0], wb = wr[1];
        lg[0] = fmaf(xv[j], wa.x, lg[0]);
        lg[1] = fmaf(xv[j], wa.y, lg[1]);
        lg[2] = fmaf(xv[j], wa.z, lg[2]);
        lg[3] = fmaf(xv[j], wa.w, lg[3]);
        lg[4] = fmaf(xv[j], wb.x, lg[4]);
        lg[5] = fmaf(xv[j], wb.y, lg[5]);
        lg[6] = fmaf(xv[j], wb.z, lg[6]);
        lg[7] = fmaf(xv[j], wb.w, lg[7]);
    }
#pragma unroll
    for (int off = 32; off > 0; off >>= 1) {
#pragma unroll
        for (int e = 0; e < 8; e++) lg[e] += __shfl_xor(lg[e], off, 64);
    }
    float l0 = lg[0]; int i0 = 0;
#pragma unroll
    for (int e = 1; e < 8; e++) { if (lg[e] > l0) { l0 = lg[e]; i0 = e; } }
    float l1 = -3.4e38f;
#pragma unroll
    for (int e = 0; e < 8; e++) { if (e != i0 && lg[e] > l1) l1 = lg[e]; }
    float p1 = expf(l1 - l0);
    float sa = 1.0f / (1.0f + p1);
    if (lane == 0) { s0[t] = sa; s1[t] = p1 * sa; }
}

// ---- fused batched transpose + f32->bf16 for W1 and W2 in one launch ----
__global__ void transpose_cvt2_kernel(const float* __restrict__ W1, short* __restrict__ w1t,
                                      const float* __restrict__ W2, short* __restrict__ w2t) {
    __shared__ float t[64][33];
    int b = blockIdx.y;
    int bid = blockIdx.x;
    const float* ip;
    short* op;
    int R, C, tx, ty;
    if (bid < 512) {
        R = 512; C = 2048; tx = bid & 31; ty = bid >> 5;
        ip = W1 + (size_t)b * R * C; op = w1t + (size_t)b * R * C;
    } else {
        int id = bid - 512;
        R = 2048; C = 512; tx = id & 7; ty = id >> 3;
        ip = W2 + (size_t)b * R * C; op = w2t + (size_t)b * R * C;
    }
    int c0 = tx * 64, r0 = ty * 32;
    int tid = threadIdx.x;
    int lr = tid >> 3, lc8 = (tid & 7) * 8;
    const float* src = &ip[(size_t)(r0 + lr) * C + c0 + lc8];
    float4 v0 = *(const float4*)src;
    float4 v1 = *(const float4*)(src + 4);
    t[lc8 + 0][lr] = v0.x; t[lc8 + 1][lr] = v0.y; t[lc8 + 2][lr] = v0.z; t[lc8 + 3][lr] = v0.w;
    t[lc8 + 4][lr] = v1.x; t[lc8 + 5][lr] = v1.y; t[lc8 + 6][lr] = v1.z; t[lc8 + 7][lr] = v1.w;
    __syncthreads();
    int sc = tid >> 2, sk = (tid & 3) * 8;
    s16x8 o;
#pragma unroll
    for (int j = 0; j < 8; j++) o[j] = f2bf(t[sc][sk + j]);
    *(s16x8*)&op[(size_t)(c0 + sc) * R + r0 + sk] = o;
}

// ---- GEMM1 + fused activation (round-10 exact, passing) ----
__launch_bounds__(256, 2)
__global__ void gemm1_kernel(const short* __restrict__ xb, const short* __restrict__ w1t,
                             const float* __restrict__ s0v, const float* __restrict__ s1v,
                             const float* __restrict__ b1, short* __restrict__ H) {
    __shared__ short Al[128 * 64];
    __shared__ short Bl[128 * 64];
    __shared__ float ls0[128], ls1[128], lb1[128];
    int d = blockIdx.x;
    int e = d & 7;
    int tno = d >> 3;
    int n0 = (tno & 15) * 128;
    int m0 = (tno >> 4) * 128;
    const short* A = xb;
    const short* B = w1t + (size_t)e * DFF * DMODEL;
    short* Ho = H + (size_t)e * TOKENS * DFF;

    int tid = threadIdx.x;
    int lane = tid & 63;
    int w = tid >> 6;
    int m_off = (w >> 1) * 64;
    int n_off = (w & 1) * 64;

    if (tid < 128) {
        ls0[tid] = s0v[m0 + tid];
        ls1[tid] = s1v[m0 + tid];
        lb1[tid] = b1[(size_t)e * DFF + n0 + tid];
    }

    int srow = lane >> 3;
    int schunk = (lane & 7) ^ srow;
    int q = lane >> 4;

    f32x4 acc[4][4];
#pragma unroll
    for (int mi = 0; mi < 4; mi++)
#pragma unroll
        for (int ni = 0; ni < 4; ni++) acc[mi][ni] = (f32x4){0.f, 0.f, 0.f, 0.f};

    for (int k0 = 0; k0 < DMODEL; k0 += 64) {
#pragma unroll
        for (int c = 0; c < 4; c++) {
            int seg = c * 4 + w;
            gload_lds16(&A[(size_t)(m0 + seg * 8 + srow) * DMODEL + k0 + schunk * 8],
                        &Al[seg * 512]);
            gload_lds16(&B[(size_t)(n0 + seg * 8 + srow) * DMODEL + k0 + schunk * 8],
                        &Bl[seg * 512]);
        }
        __syncthreads();
#pragma unroll
        for (int ks = 0; ks < 2; ks++) {
            s16x8 af[4], bfr[4];
#pragma unroll
            for (int mi = 0; mi < 4; mi++) {
                int r = m_off + mi * 16 + (lane & 15);
                int cp = (ks * 4 + q) ^ (r & 7);
                af[mi] = *(const s16x8*)&Al[r * 64 + cp * 8];
            }
#pragma unroll
            for (int ni = 0; ni < 4; ni++) {
                int r = n_off + ni * 16 + (lane & 15);
                int cp = (ks * 4 + q) ^ (r & 7);
                bfr[ni] = *(const s16x8*)&Bl[r * 64 + cp * 8];
            }
#pragma unroll
            for (int mi = 0; mi < 4; mi++)
#pragma unroll
                for (int ni = 0; ni < 4; ni++)
                    acc[mi][ni] = __builtin_amdgcn_mfma_f32_16x16x32_bf16(bfr[ni], af[mi], acc[mi][ni], 0, 0, 0);
        }
        __syncthreads();
    }
    {
        int mcol = lane & 15;
        int nrow4 = (lane >> 4) * 4;
#pragma unroll
        for (int mi = 0; mi < 4; mi++) {
            int m = m_off + mi * 16 + mcol;
            float sa = ls0[m], sb = ls1[m];
#pragma unroll
            for (int ni = 0; ni < 4; ni++) {
                int nb = n_off + ni * 16 + nrow4;
                float4 bb = *(const float4*)&lb1[nb];
                float bv[4] = {bb.x, bb.y, bb.z, bb.w};
                float h4[4];
#pragma unroll
                for (int r = 0; r < 4; r++) {
                    float a = acc[mi][ni][r];
                    h4[r] = gelu_pair(fmaf(sa, a, bv[r]), fmaf(sb, a, bv[r]));
                }
                u32x2 pv;
                pv[0] = cvtpk_bf16(h4[0], h4[1]);
                pv[1] = cvtpk_bf16(h4[2], h4[3]);
                *(u32x2*)&Ho[(size_t)(m0 + m) * DFF + n0 + nb] = pv;
            }
        }
    }
}

// ------- GEMM2 (pure): part[e] = H[e] @ W2[e] -------
// 8-phase-class schedule: 256x256 tile, BK=64, 8 waves (2M x 4N), double-buffered 128KB LDS,
// 4 phases/K-tile {stage-issue || ds_read operand-half || 16-MFMA quadrant}, counted vmcnt.
// Ledger: 8 loads/wave/tile issued P1(A0,B0=4)+P2(A1,B1=4); at next P1 outstanding=8+4 ->
// vmcnt(4) ensures compute buffer landed; vmcnt(0) only for the final tile.
__launch_bounds__(512, 1)
__global__ void gemm2_kernel(const short* __restrict__ H, const short* __restrict__ w2t,
                             short* __restrict__ partb) {
    __shared__ short Al[2][256 * 64];   // 64 KB
    __shared__ short Bl[2][256 * 64];   // 64 KB
    int d = blockIdx.x;
    int e = d & 7;                      // expert -> XCD pin
    int tno = d >> 3;                   // 0..31
    int n0 = (tno & 1) * 256;
    int m0 = (tno >> 1) * 256;
    const short* A = H + (size_t)e * TOKENS * DFF + (size_t)m0 * DFF;    // [256][2048]
    const short* B = w2t + (size_t)e * DMODEL * DFF + (size_t)n0 * DFF;  // [256][2048]
    short* Pe = partb + (size_t)e * TOKENS * DMODEL;

    int tid = threadIdx.x;
    int lane = tid & 63;
    int w = tid >> 6;                   // 0..7
    int wr = w >> 2;                    // 0..1 (M)
    int wc = w & 3;                     // 0..3 (N)
    int q = lane >> 4;
    int l15 = lane & 15;

    int srow = lane >> 3;
    int schunk = (lane & 7) ^ srow;

    f32x4 acc[8][4];
#pragma unroll
    for (int mi = 0; mi < 8; mi++)
#pragma unroll
        for (int ni = 0; ni < 4; ni++) acc[mi][ni] = (f32x4){0.f, 0.f, 0.f, 0.f};

    const int NT = DFF / 64;            // 32 K-tiles

    // stage half h (0:rows 0-127, 1:rows 128-255) of A or B tile k0 into buf
#define STAGE_HALF(SRC, DSTBUF, K0, HH)                                            \
    {                                                                              \
        _Pragma("unroll")                                                          \
        for (int c = 0; c < 2; c++) {                                              \
            int seg = (HH) * 16 + c * 8 + w;                                       \
            gload_lds16(&SRC[(size_t)(seg * 8 + srow) * DFF + (K0) + schunk * 8],  \
                        &DSTBUF[seg * 512]);                                       \
        }                                                                          \
    }

    // prologue: stage tile 0 fully into buf 0 (8 loads/wave)
    STAGE_HALF(A, (&Al[0][0]), 0, 0)
    STAGE_HALF(A, (&Al[0][0]), 0, 1)
    STAGE_HALF(B, (&Bl[0][0]), 0, 0)
    STAGE_HALF(B, (&Bl[0][0]), 0, 1)

    for (int t = 0; t < NT; t++) {
        int db = t & 1;
        const short* Ac = &Al[db][0];
        const short* Bc = &Bl[db][0];
        short* An = &Al[db ^ 1][0];
        short* Bn = &Bl[db ^ 1][0];
        int k1 = (t + 1) * 64;
        bool more = (t + 1 < NT);

        s16x8 af[4][2], bfA[2][2], bfB[2][2];

        // ---- P1: stage A0,B0(t+1); vmcnt; barrier; read A-mhalf0 + B-nhalf0; MFMA Q(0,0)
        if (more) {
            STAGE_HALF(A, An, k1, 0)
            STAGE_HALF(B, Bn, k1, 0)
            asm volatile("s_waitcnt vmcnt(4)" ::: "memory");
        } else {
            asm volatile("s_waitcnt vmcnt(0)" ::: "memory");
        }
        __builtin_amdgcn_s_barrier();
        MEMFENCE;
#pragma unroll
        for (int mi = 0; mi < 4; mi++) {
            int r = wr * 128 + mi * 16 + l15;
#pragma unroll
            for (int ks = 0; ks < 2; ks++) {
                int cp = (ks * 4 + q) ^ (r & 7);
                af[mi][ks] = *(const s16x8*)&Ac[r * 64 + cp * 8];
            }
        }
#pragma unroll
        for (int ni = 0; ni < 2; ni++) {
            int r = wc * 64 + ni * 16 + l15;
#pragma unroll
            for (int ks = 0; ks < 2; ks++) {
                int cp = (ks * 4 + q) ^ (r & 7);
                bfA[ni][ks] = *(const s16x8*)&Bc[r * 64 + cp * 8];
            }
        }
        __builtin_amdgcn_s_setprio(1);
#pragma unroll
        for (int ks = 0; ks < 2; ks++)
#pragma unroll
            for (int mi = 0; mi < 4; mi++)
#pragma unroll
                for (int ni = 0; ni < 2; ni++)
                    acc[mi][ni] = __builtin_amdgcn_mfma_f32_16x16x32_bf16(bfA[ni][ks], af[mi][ks], acc[mi][ni], 0, 0, 0);
        __builtin_amdgcn_s_setprio(0);
        MEMFENCE;
        __builtin_amdgcn_s_barrier();
        MEMFENCE;

        // ---- P2: stage A1,B1(t+1); read B-nhalf1; MFMA Q(0,1)
        if (more) {
            STAGE_HALF(A, An, k1, 1)
            STAGE_HALF(B, Bn, k1, 1)
        }
#pragma unroll
        for (int ni = 0; ni < 2; ni++) {
            int r = wc * 64 + (ni + 2) * 16 + l15;
#pragma unroll
            for (int ks = 0; ks < 2; ks++) {
                int cp = (ks * 4 + q) ^ (r & 7);
                bfB[ni][ks] = *(const s16x8*)&Bc[r * 64 + cp * 8];
            }
        }
        __builtin_amdgcn_s_setprio(1);
#pragma unroll
        for (int ks = 0; ks < 2; ks++)
#pragma unroll
            for (int mi = 0; mi < 4; mi++)
#pragma unroll
                for (int ni = 0; ni < 2; ni++)
                    acc[mi][ni + 2] = __builtin_amdgcn_mfma_f32_16x16x32_bf16(bfB[ni][ks], af[mi][ks], acc[mi][ni + 2], 0, 0, 0);
        __builtin_amdgcn_s_setprio(0);
        MEMFENCE;
        __builtin_amdgcn_s_barrier();
        MEMFENCE;

        // ---- P3: read A-mhalf1; MFMA Q(1,0) (reuses bfA)
#pragma unroll
        for (int mi = 0; mi < 4; mi++) {
            int r = wr * 128 + (mi + 4) * 16 + l15;
#pragma unroll
            for (int ks = 0; ks < 2; ks++) {
                int cp = (ks * 4 + q) ^ (r & 7);
                af[mi][ks] = *(const s16x8*)&Ac[r * 64 + cp * 8];
            }
        }
        __builtin_amdgcn_s_setprio(1);
#pragma unroll
        for (int ks = 0; ks < 2; ks++)
#pragma unroll
            for (int mi = 0; mi < 4; mi++)
#pragma unroll
                for (int ni = 0; ni < 2; ni++)
                    acc[mi + 4][ni] = __builtin_amdgcn_mfma_f32_16x16x32_bf16(bfA[ni][ks], af[mi][ks], acc[mi + 4][ni], 0, 0, 0);
        __builtin_amdgcn_s_setprio(0);
        MEMFENCE;
        __builtin_amdgcn_s_barrier();
        MEMFENCE;

        // ---- P4: MFMA Q(1,1) (af mhalf1 x bfB); trailing barrier frees buf db for overwrite
        __builtin_amdgcn_s_setprio(1);
#pragma unroll
        for (int ks = 0; ks < 2; ks++)
#pragma unroll
            for (int mi = 0; mi < 4; mi++)
#pragma unroll
                for (int ni = 0; ni < 2; ni++)
                    acc[mi + 4][ni + 2] = __builtin_amdgcn_mfma_f32_16x16x32_bf16(bfB[ni][ks], af[mi][ks], acc[mi + 4][ni + 2], 0, 0, 0);
        __builtin_amdgcn_s_setprio(0);
        MEMFENCE;
        __builtin_amdgcn_s_barrier();
        MEMFENCE;
    }
#undef STAGE_HALF

    // epilogue: swapped layout -> N-contiguous bf16 packs
    {
        int nrow4 = (lane >> 4) * 4;
#pragma unroll
        for (int mi = 0; mi < 8; mi++) {
            int m = m0 + wr * 128 + mi * 16 + l15;
#pragma unroll
            for (int ni = 0; ni < 4; ni++) {
                int nb = n0 + wc * 64 + ni * 16 + nrow4;
                u32x2 pv;
                pv[0] = cvtpk_bf16(acc[mi][ni][0], acc[mi][ni][1]);
                pv[1] = cvtpk_bf16(acc[mi][ni][2], acc[mi][ni][3]);
                *(u32x2*)&Pe[(size_t)m * DMODEL + nb] = pv;
            }
        }
    }
}

// ---------------- reduce over experts (bf16 part) + 2*b2_sum ----------------
__global__ void reduce_kernel(const short* __restrict__ partb, const float* __restrict__ b2,
                              float* __restrict__ out) {
    int i = (blockIdx.x * 256 + threadIdx.x) * 8;
    if (i >= TOKENS * DMODEL) return;
    int n = i & (DMODEL - 1);
    float s[8] = {0.f, 0.f, 0.f, 0.f, 0.f, 0.f, 0.f, 0.f};
#pragma unroll
    for (int e = 0; e < 8; e++) {
        s16x8 p = *(const s16x8*)&partb[(size_t)e * TOKENS * DMODEL + i];
        float4 ba = *(const float4*)&b2[(size_t)e * DMODEL + n];
        float4 bb = *(const float4*)&b2[(size_t)e * DMODEL + n + 4];
        s[0] += bf2f(p[0]) + 2.f * ba.x;
        s[1] += bf2f(p[1]) + 2.f * ba.y;
        s[2] += bf2f(p[2]) + 2.f * ba.z;
        s[3] += bf2f(p[3]) + 2.f * ba.w;
        s[4] += bf2f(p[4]) + 2.f * bb.x;
        s[5] += bf2f(p[5]) + 2.f * bb.y;
        s[6] += bf2f(p[6]) + 2.f * bb.z;
        s[7] += bf2f(p[7]) + 2.f * bb.w;
    }
    float4 o0 = {s[0], s[1], s[2], s[3]};
    float4 o1 = {s[4], s[5], s[6], s[7]};
    *(float4*)&out[i] = o0;
    *(float4*)&out[i + 4] = o1;
}

extern "C" void kernel_launch(void* const* d_in, const int* in_sizes, int n_in,
                              void* d_out, int out_size, void* d_ws, size_t ws_size,
                              hipStream_t stream) {
    const float* x  = (const float*)d_in[0];
    const float* Wg = (const float*)d_in[1];
    const float* W1 = (const float*)d_in[2];
    const float* b1 = (const float*)d_in[3];
    const float* W2 = (const float*)d_in[4];
    const float* b2 = (const float*)d_in[5];
    float* out = (float*)d_out;

    char* ws = (char*)d_ws;
    float* s0  = (float*)(ws);
    float* s1  = (float*)(ws + 16384);
    short* xb  = (short*)(ws + 32768);
    short* w1t = (short*)(ws + 32768 + 4194304);
    short* w2t = (short*)(ws + 32768 + 4194304 + 16777216);
    short* Hb  = (short*)(ws + 32768 + 4194304 + 2ull * 16777216);               // 128MB
    short* partb = (short*)(ws + 32768 + 4194304 + 2ull * 16777216 + 134217728); // 33.5MB bf16

    hipLaunchKernelGGL(gate_cvt_kernel, dim3(1024), dim3(256), 0, stream, x, Wg, s0, s1, xb);
    hipLaunchKernelGGL(transpose_cvt2_kernel, dim3(1024, 8), dim3(256), 0, stream, W1, w1t, W2, w2t);
    hipLaunchKernelGGL(gemm1_kernel, dim3(4096), dim3(256), 0, stream, xb, w1t, s0, s1, b1, Hb);
    hipLaunchKernelGGL(gemm2_kernel, dim3(256), dim3(512), 0, stream, Hb, w2t, partb);
    hipLaunchKernelGGL(reduce_kernel, dim3(1024), dim3(256), 0, stream, partb, b2, out);
}

// Round 12
// 206.265 us; speedup vs baseline: 1.0529x; 1.0529x over previous
//
#include <hip/hip_runtime.h>
#include <hip/hip_bf16.h>
#include <cstdint>

#define TOKENS 4096
#define DMODEL 512
#define NEXP 8
#define DFF 2048

typedef short s16x8 __attribute__((ext_vector_type(8)));
typedef short s16x4 __attribute__((ext_vector_type(4)));
typedef float f32x4 __attribute__((ext_vector_type(4)));
typedef unsigned int u32x2 __attribute__((ext_vector_type(2)));

__device__ __forceinline__ float bf2f(short h) {
    unsigned int u = ((unsigned int)(unsigned short)h) << 16;
    return __uint_as_float(u);
}
__device__ __forceinline__ short f2bf(float f) {
    unsigned int u = __float_as_uint(f);
    u += 0x7fffu + ((u >> 16) & 1u);
    return (short)(u >> 16);
}
__device__ __forceinline__ unsigned int cvtpk_bf16(float a, float b) {
    unsigned int r;
    asm volatile("v_cvt_pk_bf16_f32 %0, %1, %2" : "=v"(r) : "v"(a), "v"(b));
    return r;
}
// exact pair: gelu(x0)+gelu(x1) with single rcp; tanh-form, constants pre-scaled by log2(e)
#define GP_C0 2.3022084f
#define GP_C1 0.10294330f
__device__ __forceinline__ float gelu_pair(float x0, float x1) {
    float z0 = x0 * fmaf(x0 * x0, GP_C1, GP_C0);
    float z1 = x1 * fmaf(x1 * x1, GP_C1, GP_C0);
    float e0 = __builtin_amdgcn_exp2f(z0);
    float e1 = __builtin_amdgcn_exp2f(z1);
    float t0 = 1.0f + e0, t1 = 1.0f + e1;
    float R = __builtin_amdgcn_rcpf(t0 * t1);
    float num = fmaf(x0, t1, x1 * t0);
    return fmaf(-num, R, x0 + x1);
}
__device__ __forceinline__ void gload_lds16(const void* g, void* l) {
    __builtin_amdgcn_global_load_lds((const __attribute__((address_space(1))) void*)g,
                                     (__attribute__((address_space(3))) void*)l, 16, 0, 0);
}

// ---------------- gate (+ x->bf16 fused) ----------------
__global__ void gate_cvt_kernel(const float* __restrict__ x, const float* __restrict__ Wg,
                                float* __restrict__ s0, float* __restrict__ s1,
                                short* __restrict__ xb) {
    int wave = threadIdx.x >> 6;
    int lane = threadIdx.x & 63;
    int t = blockIdx.x * 4 + wave;
    const float* xr = x + (size_t)t * DMODEL + lane * 8;
    float4 xa = *(const float4*)(xr);
    float4 xv2 = *(const float4*)(xr + 4);
    float xv[8] = {xa.x, xa.y, xa.z, xa.w, xv2.x, xv2.y, xv2.z, xv2.w};
    s16x8 v;
#pragma unroll
    for (int j = 0; j < 8; j++) v[j] = f2bf(xv[j]);
    *(s16x8*)&xb[(size_t)t * DMODEL + lane * 8] = v;

    float lg[8];
#pragma unroll
    for (int e = 0; e < 8; e++) lg[e] = 0.f;
#pragma unroll
    for (int j = 0; j < 8; j++) {
        const float4* wr = (const float4*)(Wg + (size_t)(lane * 8 + j) * NEXP);
        float4 wa = wr[0], wb = wr[1];
        lg[0] = fmaf(xv[j], wa.x, lg[0]);
        lg[1] = fmaf(xv[j], wa.y, lg[1]);
        lg[2] = fmaf(xv[j], wa.z, lg[2]);
        lg[3] = fmaf(xv[j], wa.w, lg[3]);
        lg[4] = fmaf(xv[j], wb.x, lg[4]);
        lg[5] = fmaf(xv[j], wb.y, lg[5]);
        lg[6] = fmaf(xv[j], wb.z, lg[6]);
        lg[7] = fmaf(xv[j], wb.w, lg[7]);
    }
#pragma unroll
    for (int off = 32; off > 0; off >>= 1) {
#pragma unroll
        for (int e = 0; e < 8; e++) lg[e] += __shfl_xor(lg[e], off, 64);
    }
    float l0 = lg[0]; int i0 = 0;
#pragma unroll
    for (int e = 1; e < 8; e++) { if (lg[e] > l0) { l0 = lg[e]; i0 = e; } }
    float l1 = -3.4e38f;
#pragma unroll
    for (int e = 0; e < 8; e++) { if (e != i0 && lg[e] > l1) l1 = lg[e]; }
    float p1 = expf(l1 - l0);
    float sa = 1.0f / (1.0f + p1);
    if (lane == 0) { s0[t] = sa; s1[t] = p1 * sa; }
}

// ---- fused batched transpose + f32->bf16 for W1 and W2 in one launch ----
__global__ void transpose_cvt2_kernel(const float* __restrict__ W1, short* __restrict__ w1t,
                                      const float* __restrict__ W2, short* __restrict__ w2t) {
    __shared__ float t[64][33];
    int b = blockIdx.y;
    int bid = blockIdx.x;
    const float* ip;
    short* op;
    int R, C, tx, ty;
    if (bid < 512) {
        R = 512; C = 2048; tx = bid & 31; ty = bid >> 5;
        ip = W1 + (size_t)b * R * C; op = w1t + (size_t)b * R * C;
    } else {
        int id = bid - 512;
        R = 2048; C = 512; tx = id & 7; ty = id >> 3;
        ip = W2 + (size_t)b * R * C; op = w2t + (size_t)b * R * C;
    }
    int c0 = tx * 64, r0 = ty * 32;
    int tid = threadIdx.x;
    int lr = tid >> 3, lc8 = (tid & 7) * 8;
    const float* src = &ip[(size_t)(r0 + lr) * C + c0 + lc8];
    float4 v0 = *(const float4*)src;
    float4 v1 = *(const float4*)(src + 4);
    t[lc8 + 0][lr] = v0.x; t[lc8 + 1][lr] = v0.y; t[lc8 + 2][lr] = v0.z; t[lc8 + 3][lr] = v0.w;
    t[lc8 + 4][lr] = v1.x; t[lc8 + 5][lr] = v1.y; t[lc8 + 6][lr] = v1.z; t[lc8 + 7][lr] = v1.w;
    __syncthreads();
    int sc = tid >> 2, sk = (tid & 3) * 8;
    s16x8 o;
#pragma unroll
    for (int j = 0; j < 8; j++) o[j] = f2bf(t[sc][sk + j]);
    *(s16x8*)&op[(size_t)(c0 + sc) * R + r0 + sk] = o;
}

// ---- GEMM1 + fused activation: H[e] = gelu(s0*(x@W1[e])+b1) + gelu(s1*(x@W1[e])+b1) ----
// swapped-operand MFMA: acc regs are N-contiguous -> packed dwordx2 H-stores
__launch_bounds__(256, 2)
__global__ void gemm1_kernel(const short* __restrict__ xb, const short* __restrict__ w1t,
                             const float* __restrict__ s0v, const float* __restrict__ s1v,
                             const float* __restrict__ b1, short* __restrict__ H) {
    __shared__ short Al[128 * 64];
    __shared__ short Bl[128 * 64];
    __shared__ float ls0[128], ls1[128], lb1[128];
    int d = blockIdx.x;
    int e = d & 7;
    int tno = d >> 3;
    int n0 = (tno & 15) * 128;
    int m0 = (tno >> 4) * 128;
    const short* A = xb;
    const short* B = w1t + (size_t)e * DFF * DMODEL;
    short* Ho = H + (size_t)e * TOKENS * DFF;

    int tid = threadIdx.x;
    int lane = tid & 63;
    int w = tid >> 6;
    int m_off = (w >> 1) * 64;
    int n_off = (w & 1) * 64;

    if (tid < 128) {
        ls0[tid] = s0v[m0 + tid];
        ls1[tid] = s1v[m0 + tid];
        lb1[tid] = b1[(size_t)e * DFF + n0 + tid];
    }

    int srow = lane >> 3;
    int schunk = (lane & 7) ^ srow;
    int q = lane >> 4;

    f32x4 acc[4][4];
#pragma unroll
    for (int mi = 0; mi < 4; mi++)
#pragma unroll
        for (int ni = 0; ni < 4; ni++) acc[mi][ni] = (f32x4){0.f, 0.f, 0.f, 0.f};

    for (int k0 = 0; k0 < DMODEL; k0 += 64) {
#pragma unroll
        for (int c = 0; c < 4; c++) {
            int seg = c * 4 + w;
            gload_lds16(&A[(size_t)(m0 + seg * 8 + srow) * DMODEL + k0 + schunk * 8],
                        &Al[seg * 512]);
            gload_lds16(&B[(size_t)(n0 + seg * 8 + srow) * DMODEL + k0 + schunk * 8],
                        &Bl[seg * 512]);
        }
        __syncthreads();
#pragma unroll
        for (int ks = 0; ks < 2; ks++) {
            s16x8 af[4], bfr[4];
#pragma unroll
            for (int mi = 0; mi < 4; mi++) {
                int r = m_off + mi * 16 + (lane & 15);
                int cp = (ks * 4 + q) ^ (r & 7);
                af[mi] = *(const s16x8*)&Al[r * 64 + cp * 8];
            }
#pragma unroll
            for (int ni = 0; ni < 4; ni++) {
                int r = n_off + ni * 16 + (lane & 15);
                int cp = (ks * 4 + q) ^ (r & 7);
                bfr[ni] = *(const s16x8*)&Bl[r * 64 + cp * 8];
            }
            // swapped operands: D[row->N][col->M]
#pragma unroll
            for (int mi = 0; mi < 4; mi++)
#pragma unroll
                for (int ni = 0; ni < 4; ni++)
                    acc[mi][ni] = __builtin_amdgcn_mfma_f32_16x16x32_bf16(bfr[ni], af[mi], acc[mi][ni], 0, 0, 0);
        }
        __syncthreads();
    }
    // epilogue: per lane M = lane&15 (col), N = (lane>>4)*4 + reg (row) -> N-contiguous packs
    {
        int mcol = lane & 15;
        int nrow4 = (lane >> 4) * 4;
#pragma unroll
        for (int mi = 0; mi < 4; mi++) {
            int m = m_off + mi * 16 + mcol;
            float sa = ls0[m], sb = ls1[m];
#pragma unroll
            for (int ni = 0; ni < 4; ni++) {
                int nb = n_off + ni * 16 + nrow4;
                float4 bb = *(const float4*)&lb1[nb];
                float bv[4] = {bb.x, bb.y, bb.z, bb.w};
                float h4[4];
#pragma unroll
                for (int r = 0; r < 4; r++) {
                    float a = acc[mi][ni][r];
                    h4[r] = gelu_pair(fmaf(sa, a, bv[r]), fmaf(sb, a, bv[r]));
                }
                u32x2 pv;
                pv[0] = cvtpk_bf16(h4[0], h4[1]);
                pv[1] = cvtpk_bf16(h4[2], h4[3]);
                *(u32x2*)&Ho[(size_t)(m0 + m) * DFF + n0 + nb] = pv;
            }
        }
    }
}

// ------- GEMM2 (pure): part[e] = H[e] @ W2[e]  (128x128 tile, BK=64, 4 waves) -------
// bf16 part output (cvtpk packed u32x2 stores — same pattern as gemm1 H-store)
__launch_bounds__(256, 2)
__global__ void gemm2_kernel(const short* __restrict__ H, const short* __restrict__ w2t,
                             short* __restrict__ partb) {
    __shared__ short Al[128 * 64];
    __shared__ short Bl[128 * 64];
    int d = blockIdx.x;
    int e = d & 7;                   // expert -> XCD pin
    int tno = d >> 3;                // 0..127
    int n0 = (tno & 3) * 128;
    int m0 = (tno >> 2) * 128;
    const short* A = H + (size_t)e * TOKENS * DFF;     // [4096][2048]
    const short* B = w2t + (size_t)e * DMODEL * DFF;   // [512][2048] = W2^T
    short* Pe = partb + (size_t)e * TOKENS * DMODEL;

    int tid = threadIdx.x;
    int lane = tid & 63;
    int w = tid >> 6;
    int m_off = (w >> 1) * 64;
    int n_off = (w & 1) * 64;

    int srow = lane >> 3;
    int schunk = (lane & 7) ^ srow;
    int q = lane >> 4;

    f32x4 acc[4][4];
#pragma unroll
    for (int mi = 0; mi < 4; mi++)
#pragma unroll
        for (int ni = 0; ni < 4; ni++) acc[mi][ni] = (f32x4){0.f, 0.f, 0.f, 0.f};

    for (int k0 = 0; k0 < DFF; k0 += 64) {
#pragma unroll
        for (int c = 0; c < 4; c++) {
            int seg = c * 4 + w;
            gload_lds16(&A[(size_t)(m0 + seg * 8 + srow) * DFF + k0 + schunk * 8],
                        &Al[seg * 512]);
            gload_lds16(&B[(size_t)(n0 + seg * 8 + srow) * DFF + k0 + schunk * 8],
                        &Bl[seg * 512]);
        }
        __syncthreads();
#pragma unroll
        for (int ks = 0; ks < 2; ks++) {
            s16x8 af[4], bfr[4];
#pragma unroll
            for (int mi = 0; mi < 4; mi++) {
                int r = m_off + mi * 16 + (lane & 15);
                int cp = (ks * 4 + q) ^ (r & 7);
                af[mi] = *(const s16x8*)&Al[r * 64 + cp * 8];
            }
#pragma unroll
            for (int ni = 0; ni < 4; ni++) {
                int r = n_off + ni * 16 + (lane & 15);
                int cp = (ks * 4 + q) ^ (r & 7);
                bfr[ni] = *(const s16x8*)&Bl[r * 64 + cp * 8];
            }
            // swapped operands: D[row->N][col->M]
#pragma unroll
            for (int mi = 0; mi < 4; mi++)
#pragma unroll
                for (int ni = 0; ni < 4; ni++)
                    acc[mi][ni] = __builtin_amdgcn_mfma_f32_16x16x32_bf16(bfr[ni], af[mi], acc[mi][ni], 0, 0, 0);
        }
        __syncthreads();
    }

    {
        int mcol = lane & 15;
        int nrow4 = (lane >> 4) * 4;
#pragma unroll
        for (int mi = 0; mi < 4; mi++) {
            int m = m0 + m_off + mi * 16 + mcol;
#pragma unroll
            for (int ni = 0; ni < 4; ni++) {
                int nb = n0 + n_off + ni * 16 + nrow4;
                u32x2 pv;
                pv[0] = cvtpk_bf16(acc[mi][ni][0], acc[mi][ni][1]);
                pv[1] = cvtpk_bf16(acc[mi][ni][2], acc[mi][ni][3]);
                *(u32x2*)&Pe[(size_t)m * DMODEL + nb] = pv;
            }
        }
    }
}

// ---------------- reduce over experts (bf16 part) + 2*b2_sum ----------------
__global__ void reduce_kernel(const short* __restrict__ partb, const float* __restrict__ b2,
                              float* __restrict__ out) {
    int i = (blockIdx.x * 256 + threadIdx.x) * 8;
    if (i >= TOKENS * DMODEL) return;
    int n = i & (DMODEL - 1);
    float s[8] = {0.f, 0.f, 0.f, 0.f, 0.f, 0.f, 0.f, 0.f};
#pragma unroll
    for (int e = 0; e < 8; e++) {
        s16x8 p = *(const s16x8*)&partb[(size_t)e * TOKENS * DMODEL + i];
        float4 ba = *(const float4*)&b2[(size_t)e * DMODEL + n];
        float4 bb = *(const float4*)&b2[(size_t)e * DMODEL + n + 4];
        s[0] += bf2f(p[0]) + 2.f * ba.x;
        s[1] += bf2f(p[1]) + 2.f * ba.y;
        s[2] += bf2f(p[2]) + 2.f * ba.z;
        s[3] += bf2f(p[3]) + 2.f * ba.w;
        s[4] += bf2f(p[4]) + 2.f * bb.x;
        s[5] += bf2f(p[5]) + 2.f * bb.y;
        s[6] += bf2f(p[6]) + 2.f * bb.z;
        s[7] += bf2f(p[7]) + 2.f * bb.w;
    }
    float4 o0 = {s[0], s[1], s[2], s[3]};
    float4 o1 = {s[4], s[5], s[6], s[7]};
    *(float4*)&out[i] = o0;
    *(float4*)&out[i + 4] = o1;
}

extern "C" void kernel_launch(void* const* d_in, const int* in_sizes, int n_in,
                              void* d_out, int out_size, void* d_ws, size_t ws_size,
                              hipStream_t stream) {
    const float* x  = (const float*)d_in[0];
    const float* Wg = (const float*)d_in[1];
    const float* W1 = (const float*)d_in[2];
    const float* b1 = (const float*)d_in[3];
    const float* W2 = (const float*)d_in[4];
    const float* b2 = (const float*)d_in[5];
    float* out = (float*)d_out;

    char* ws = (char*)d_ws;
    float* s0  = (float*)(ws);
    float* s1  = (float*)(ws + 16384);
    short* xb  = (short*)(ws + 32768);
    short* w1t = (short*)(ws + 32768 + 4194304);
    short* w2t = (short*)(ws + 32768 + 4194304 + 16777216);
    short* Hb  = (short*)(ws + 32768 + 4194304 + 2ull * 16777216);               // 128MB
    short* partb = (short*)(ws + 32768 + 4194304 + 2ull * 16777216 + 134217728); // 33.5MB bf16

    hipLaunchKernelGGL(gate_cvt_kernel, dim3(1024), dim3(256), 0, stream, x, Wg, s0, s1, xb);
    hipLaunchKernelGGL(transpose_cvt2_kernel, dim3(1024, 8), dim3(256), 0, stream, W1, w1t, W2, w2t);
    hipLaunchKernelGGL(gemm1_kernel, dim3(4096), dim3(256), 0, stream, xb, w1t, s0, s1, b1, Hb);
    hipLaunchKernelGGL(gemm2_kernel, dim3(1024), dim3(256), 0, stream, Hb, w2t, partb);
    hipLaunchKernelGGL(reduce_kernel, dim3(1024), dim3(256), 0, stream, partb, b2, out);
}

// Round 13
// 201.767 us; speedup vs baseline: 1.0764x; 1.0223x over previous
//
#include <hip/hip_runtime.h>
#include <hip/hip_bf16.h>
#include <cstdint>

#define TOKENS 4096
#define DMODEL 512
#define NEXP 8
#define DFF 2048

typedef short s16x8 __attribute__((ext_vector_type(8)));
typedef short s16x4 __attribute__((ext_vector_type(4)));
typedef float f32x4 __attribute__((ext_vector_type(4)));
typedef unsigned int u32x2 __attribute__((ext_vector_type(2)));

__device__ __forceinline__ float bf2f(short h) {
    unsigned int u = ((unsigned int)(unsigned short)h) << 16;
    return __uint_as_float(u);
}
__device__ __forceinline__ short f2bf(float f) {
    unsigned int u = __float_as_uint(f);
    u += 0x7fffu + ((u >> 16) & 1u);
    return (short)(u >> 16);
}
__device__ __forceinline__ unsigned int cvtpk_bf16(float a, float b) {
    unsigned int r;
    asm volatile("v_cvt_pk_bf16_f32 %0, %1, %2" : "=v"(r) : "v"(a), "v"(b));
    return r;
}
// exact pair: gelu(x0)+gelu(x1) with single rcp; tanh-form, constants pre-scaled by log2(e)
#define GP_C0 2.3022084f
#define GP_C1 0.10294330f
__device__ __forceinline__ float gelu_pair(float x0, float x1) {
    float z0 = x0 * fmaf(x0 * x0, GP_C1, GP_C0);
    float z1 = x1 * fmaf(x1 * x1, GP_C1, GP_C0);
    float e0 = __builtin_amdgcn_exp2f(z0);
    float e1 = __builtin_amdgcn_exp2f(z1);
    float t0 = 1.0f + e0, t1 = 1.0f + e1;
    float R = __builtin_amdgcn_rcpf(t0 * t1);
    float num = fmaf(x0, t1, x1 * t0);
    return fmaf(-num, R, x0 + x1);
}
__device__ __forceinline__ void gload_lds16(const void* g, void* l) {
    __builtin_amdgcn_global_load_lds((const __attribute__((address_space(1))) void*)g,
                                     (__attribute__((address_space(3))) void*)l, 16, 0, 0);
}

// ---- fused prep: gate (+x->bf16) AND both weight transposes in one launch ----
// blocks 0..1023: gate for 4 tokens each; blocks 1024..9215: 32x64 transpose tiles.
__global__ void prep_kernel(const float* __restrict__ x, const float* __restrict__ Wg,
                            float* __restrict__ s0, float* __restrict__ s1,
                            short* __restrict__ xb,
                            const float* __restrict__ W1, short* __restrict__ w1t,
                            const float* __restrict__ W2, short* __restrict__ w2t) {
    __shared__ float t[64][33];
    int blk = blockIdx.x;
    int tid = threadIdx.x;
    if (blk < 1024) {
        // ---------- gate + x->bf16 ----------
        int wave = tid >> 6;
        int lane = tid & 63;
        int tk = blk * 4 + wave;
        const float* xr = x + (size_t)tk * DMODEL + lane * 8;
        float4 xa = *(const float4*)(xr);
        float4 xv2 = *(const float4*)(xr + 4);
        float xv[8] = {xa.x, xa.y, xa.z, xa.w, xv2.x, xv2.y, xv2.z, xv2.w};
        s16x8 v;
#pragma unroll
        for (int j = 0; j < 8; j++) v[j] = f2bf(xv[j]);
        *(s16x8*)&xb[(size_t)tk * DMODEL + lane * 8] = v;

        float lg[8];
#pragma unroll
        for (int e = 0; e < 8; e++) lg[e] = 0.f;
#pragma unroll
        for (int j = 0; j < 8; j++) {
            const float4* wr = (const float4*)(Wg + (size_t)(lane * 8 + j) * NEXP);
            float4 wa = wr[0], wb = wr[1];
            lg[0] = fmaf(xv[j], wa.x, lg[0]);
            lg[1] = fmaf(xv[j], wa.y, lg[1]);
            lg[2] = fmaf(xv[j], wa.z, lg[2]);
            lg[3] = fmaf(xv[j], wa.w, lg[3]);
            lg[4] = fmaf(xv[j], wb.x, lg[4]);
            lg[5] = fmaf(xv[j], wb.y, lg[5]);
            lg[6] = fmaf(xv[j], wb.z, lg[6]);
            lg[7] = fmaf(xv[j], wb.w, lg[7]);
        }
#pragma unroll
        for (int off = 32; off > 0; off >>= 1) {
#pragma unroll
            for (int e = 0; e < 8; e++) lg[e] += __shfl_xor(lg[e], off, 64);
        }
        float l0 = lg[0]; int i0 = 0;
#pragma unroll
        for (int e = 1; e < 8; e++) { if (lg[e] > l0) { l0 = lg[e]; i0 = e; } }
        float l1 = -3.4e38f;
#pragma unroll
        for (int e = 0; e < 8; e++) { if (e != i0 && lg[e] > l1) l1 = lg[e]; }
        float p1 = expf(l1 - l0);
        float sa = 1.0f / (1.0f + p1);
        if (lane == 0) { s0[tk] = sa; s1[tk] = p1 * sa; }
        return;
    }
    // ---------- transpose + f32->bf16 ----------
    int id = blk - 1024;           // 0..8191
    int b = id & 7;                // expert
    int bid = id >> 3;             // 0..1023
    const float* ip;
    short* op;
    int R, C, tx, ty;
    if (bid < 512) {
        R = 512; C = 2048; tx = bid & 31; ty = bid >> 5;
        ip = W1 + (size_t)b * R * C; op = w1t + (size_t)b * R * C;
    } else {
        int id2 = bid - 512;
        R = 2048; C = 512; tx = id2 & 7; ty = id2 >> 3;
        ip = W2 + (size_t)b * R * C; op = w2t + (size_t)b * R * C;
    }
    int c0 = tx * 64, r0 = ty * 32;
    int lr = tid >> 3, lc8 = (tid & 7) * 8;
    const float* src = &ip[(size_t)(r0 + lr) * C + c0 + lc8];
    float4 v0 = *(const float4*)src;
    float4 v1 = *(const float4*)(src + 4);
    t[lc8 + 0][lr] = v0.x; t[lc8 + 1][lr] = v0.y; t[lc8 + 2][lr] = v0.z; t[lc8 + 3][lr] = v0.w;
    t[lc8 + 4][lr] = v1.x; t[lc8 + 5][lr] = v1.y; t[lc8 + 6][lr] = v1.z; t[lc8 + 7][lr] = v1.w;
    __syncthreads();
    int sc = tid >> 2, sk = (tid & 3) * 8;
    s16x8 o;
#pragma unroll
    for (int j = 0; j < 8; j++) o[j] = f2bf(t[sc][sk + j]);
    *(s16x8*)&op[(size_t)(c0 + sc) * R + r0 + sk] = o;
}

// ---- GEMM1 + fused activation: H[e] = gelu(s0*(x@W1[e])+b1) + gelu(s1*(x@W1[e])+b1) ----
// swapped-operand MFMA: acc regs are N-contiguous -> packed dwordx2 H-stores
__launch_bounds__(256, 2)
__global__ void gemm1_kernel(const short* __restrict__ xb, const short* __restrict__ w1t,
                             const float* __restrict__ s0v, const float* __restrict__ s1v,
                             const float* __restrict__ b1, short* __restrict__ H) {
    __shared__ short Al[128 * 64];
    __shared__ short Bl[128 * 64];
    __shared__ float ls0[128], ls1[128], lb1[128];
    int d = blockIdx.x;
    int e = d & 7;
    int tno = d >> 3;
    int n0 = (tno & 15) * 128;
    int m0 = (tno >> 4) * 128;
    const short* A = xb;
    const short* B = w1t + (size_t)e * DFF * DMODEL;
    short* Ho = H + (size_t)e * TOKENS * DFF;

    int tid = threadIdx.x;
    int lane = tid & 63;
    int w = tid >> 6;
    int m_off = (w >> 1) * 64;
    int n_off = (w & 1) * 64;

    if (tid < 128) {
        ls0[tid] = s0v[m0 + tid];
        ls1[tid] = s1v[m0 + tid];
        lb1[tid] = b1[(size_t)e * DFF + n0 + tid];
    }

    int srow = lane >> 3;
    int schunk = (lane & 7) ^ srow;
    int q = lane >> 4;

    f32x4 acc[4][4];
#pragma unroll
    for (int mi = 0; mi < 4; mi++)
#pragma unroll
        for (int ni = 0; ni < 4; ni++) acc[mi][ni] = (f32x4){0.f, 0.f, 0.f, 0.f};

    for (int k0 = 0; k0 < DMODEL; k0 += 64) {
#pragma unroll
        for (int c = 0; c < 4; c++) {
            int seg = c * 4 + w;
            gload_lds16(&A[(size_t)(m0 + seg * 8 + srow) * DMODEL + k0 + schunk * 8],
                        &Al[seg * 512]);
            gload_lds16(&B[(size_t)(n0 + seg * 8 + srow) * DMODEL + k0 + schunk * 8],
                        &Bl[seg * 512]);
        }
        __syncthreads();
#pragma unroll
        for (int ks = 0; ks < 2; ks++) {
            s16x8 af[4], bfr[4];
#pragma unroll
            for (int mi = 0; mi < 4; mi++) {
                int r = m_off + mi * 16 + (lane & 15);
                int cp = (ks * 4 + q) ^ (r & 7);
                af[mi] = *(const s16x8*)&Al[r * 64 + cp * 8];
            }
#pragma unroll
            for (int ni = 0; ni < 4; ni++) {
                int r = n_off + ni * 16 + (lane & 15);
                int cp = (ks * 4 + q) ^ (r & 7);
                bfr[ni] = *(const s16x8*)&Bl[r * 64 + cp * 8];
            }
            // swapped operands: D[row->N][col->M]
#pragma unroll
            for (int mi = 0; mi < 4; mi++)
#pragma unroll
                for (int ni = 0; ni < 4; ni++)
                    acc[mi][ni] = __builtin_amdgcn_mfma_f32_16x16x32_bf16(bfr[ni], af[mi], acc[mi][ni], 0, 0, 0);
        }
        __syncthreads();
    }
    // epilogue: per lane M = lane&15 (col), N = (lane>>4)*4 + reg (row) -> N-contiguous packs
    {
        int mcol = lane & 15;
        int nrow4 = (lane >> 4) * 4;
#pragma unroll
        for (int mi = 0; mi < 4; mi++) {
            int m = m_off + mi * 16 + mcol;
            float sa = ls0[m], sb = ls1[m];
#pragma unroll
            for (int ni = 0; ni < 4; ni++) {
                int nb = n_off + ni * 16 + nrow4;
                float4 bb = *(const float4*)&lb1[nb];
                float bv[4] = {bb.x, bb.y, bb.z, bb.w};
                float h4[4];
#pragma unroll
                for (int r = 0; r < 4; r++) {
                    float a = acc[mi][ni][r];
                    h4[r] = gelu_pair(fmaf(sa, a, bv[r]), fmaf(sb, a, bv[r]));
                }
                u32x2 pv;
                pv[0] = cvtpk_bf16(h4[0], h4[1]);
                pv[1] = cvtpk_bf16(h4[2], h4[3]);
                *(u32x2*)&Ho[(size_t)(m0 + m) * DFF + n0 + nb] = pv;
            }
        }
    }
}

// ------- GEMM2 (pure): part[e] = H[e] @ W2[e]  (128x128 tile, BK=64, 4 waves) -------
// bf16 part output (cvtpk packed u32x2 stores — same pattern as gemm1 H-store)
__launch_bounds__(256, 2)
__global__ void gemm2_kernel(const short* __restrict__ H, const short* __restrict__ w2t,
                             short* __restrict__ partb) {
    __shared__ short Al[128 * 64];
    __shared__ short Bl[128 * 64];
    int d = blockIdx.x;
    int e = d & 7;                   // expert -> XCD pin
    int tno = d >> 3;                // 0..127
    int n0 = (tno & 3) * 128;
    int m0 = (tno >> 2) * 128;
    const short* A = H + (size_t)e * TOKENS * DFF;     // [4096][2048]
    const short* B = w2t + (size_t)e * DMODEL * DFF;   // [512][2048] = W2^T
    short* Pe = partb + (size_t)e * TOKENS * DMODEL;

    int tid = threadIdx.x;
    int lane = tid & 63;
    int w = tid >> 6;
    int m_off = (w >> 1) * 64;
    int n_off = (w & 1) * 64;

    int srow = lane >> 3;
    int schunk = (lane & 7) ^ srow;
    int q = lane >> 4;

    f32x4 acc[4][4];
#pragma unroll
    for (int mi = 0; mi < 4; mi++)
#pragma unroll
        for (int ni = 0; ni < 4; ni++) acc[mi][ni] = (f32x4){0.f, 0.f, 0.f, 0.f};

    for (int k0 = 0; k0 < DFF; k0 += 64) {
#pragma unroll
        for (int c = 0; c < 4; c++) {
            int seg = c * 4 + w;
            gload_lds16(&A[(size_t)(m0 + seg * 8 + srow) * DFF + k0 + schunk * 8],
                        &Al[seg * 512]);
            gload_lds16(&B[(size_t)(n0 + seg * 8 + srow) * DFF + k0 + schunk * 8],
                        &Bl[seg * 512]);
        }
        __syncthreads();
#pragma unroll
        for (int ks = 0; ks < 2; ks++) {
            s16x8 af[4], bfr[4];
#pragma unroll
            for (int mi = 0; mi < 4; mi++) {
                int r = m_off + mi * 16 + (lane & 15);
                int cp = (ks * 4 + q) ^ (r & 7);
                af[mi] = *(const s16x8*)&Al[r * 64 + cp * 8];
            }
#pragma unroll
            for (int ni = 0; ni < 4; ni++) {
                int r = n_off + ni * 16 + (lane & 15);
                int cp = (ks * 4 + q) ^ (r & 7);
                bfr[ni] = *(const s16x8*)&Bl[r * 64 + cp * 8];
            }
            // swapped operands: D[row->N][col->M]
#pragma unroll
            for (int mi = 0; mi < 4; mi++)
#pragma unroll
                for (int ni = 0; ni < 4; ni++)
                    acc[mi][ni] = __builtin_amdgcn_mfma_f32_16x16x32_bf16(bfr[ni], af[mi], acc[mi][ni], 0, 0, 0);
        }
        __syncthreads();
    }

    {
        int mcol = lane & 15;
        int nrow4 = (lane >> 4) * 4;
#pragma unroll
        for (int mi = 0; mi < 4; mi++) {
            int m = m0 + m_off + mi * 16 + mcol;
#pragma unroll
            for (int ni = 0; ni < 4; ni++) {
                int nb = n0 + n_off + ni * 16 + nrow4;
                u32x2 pv;
                pv[0] = cvtpk_bf16(acc[mi][ni][0], acc[mi][ni][1]);
                pv[1] = cvtpk_bf16(acc[mi][ni][2], acc[mi][ni][3]);
                *(u32x2*)&Pe[(size_t)m * DMODEL + nb] = pv;
            }
        }
    }
}

// ---------------- reduce over experts (bf16 part) + 2*b2_sum ----------------
__global__ void reduce_kernel(const short* __restrict__ partb, const float* __restrict__ b2,
                              float* __restrict__ out) {
    int i = (blockIdx.x * 256 + threadIdx.x) * 8;
    if (i >= TOKENS * DMODEL) return;
    int n = i & (DMODEL - 1);
    float s[8] = {0.f, 0.f, 0.f, 0.f, 0.f, 0.f, 0.f, 0.f};
#pragma unroll
    for (int e = 0; e < 8; e++) {
        s16x8 p = *(const s16x8*)&partb[(size_t)e * TOKENS * DMODEL + i];
        float4 ba = *(const float4*)&b2[(size_t)e * DMODEL + n];
        float4 bb = *(const float4*)&b2[(size_t)e * DMODEL + n + 4];
        s[0] += bf2f(p[0]) + 2.f * ba.x;
        s[1] += bf2f(p[1]) + 2.f * ba.y;
        s[2] += bf2f(p[2]) + 2.f * ba.z;
        s[3] += bf2f(p[3]) + 2.f * ba.w;
        s[4] += bf2f(p[4]) + 2.f * bb.x;
        s[5] += bf2f(p[5]) + 2.f * bb.y;
        s[6] += bf2f(p[6]) + 2.f * bb.z;
        s[7] += bf2f(p[7]) + 2.f * bb.w;
    }
    float4 o0 = {s[0], s[1], s[2], s[3]};
    float4 o1 = {s[4], s[5], s[6], s[7]};
    *(float4*)&out[i] = o0;
    *(float4*)&out[i + 4] = o1;
}

extern "C" void kernel_launch(void* const* d_in, const int* in_sizes, int n_in,
                              void* d_out, int out_size, void* d_ws, size_t ws_size,
                              hipStream_t stream) {
    const float* x  = (const float*)d_in[0];
    const float* Wg = (const float*)d_in[1];
    const float* W1 = (const float*)d_in[2];
    const float* b1 = (const float*)d_in[3];
    const float* W2 = (const float*)d_in[4];
    const float* b2 = (const float*)d_in[5];
    float* out = (float*)d_out;

    char* ws = (char*)d_ws;
    float* s0  = (float*)(ws);
    float* s1  = (float*)(ws + 16384);
    short* xb  = (short*)(ws + 32768);
    short* w1t = (short*)(ws + 32768 + 4194304);
    short* w2t = (short*)(ws + 32768 + 4194304 + 16777216);
    short* Hb  = (short*)(ws + 32768 + 4194304 + 2ull * 16777216);               // 128MB
    short* partb = (short*)(ws + 32768 + 4194304 + 2ull * 16777216 + 134217728); // 33.5MB bf16

    hipLaunchKernelGGL(prep_kernel, dim3(9216), dim3(256), 0, stream,
                       x, Wg, s0, s1, xb, W1, w1t, W2, w2t);
    hipLaunchKernelGGL(gemm1_kernel, dim3(4096), dim3(256), 0, stream, xb, w1t, s0, s1, b1, Hb);
    hipLaunchKernelGGL(gemm2_kernel, dim3(1024), dim3(256), 0, stream, Hb, w2t, partb);
    hipLaunchKernelGGL(reduce_kernel, dim3(1024), dim3(256), 0, stream, partb, b2, out);
}